// Round 1
// baseline (122.356 us; speedup 1.0000x reference)
//
#include <hip/hip_runtime.h>
#include <hip/hip_fp16.h>

// W8X8Linear: per-row int8 quant (x and w), int8 GEMM via MFMA, dequant+bias.
// M=B*S=32768, N=1024, K=1024 (derived from in_sizes at launch).
//
// Exact-replication notes:
//  - jnp.round == round-half-even == rintf (v_rndne_f32)
//  - scale computed as 127.0f/max (fp32 div) then fp32 mul, like the reference
//  - int32 accumulation == reference's fp32 einsum (|acc| < 2^24, exact)
//  - dequant: fp32 div by 16129, fp16 RN cast, fp32 * (xmax*wmax) + bias

typedef int i32x4 __attribute__((ext_vector_type(4)));

#define BM 128
#define BN 128
#define BK 64

// ---------------- quantize: one block per row, K=1024, 256 threads ----------
__global__ __launch_bounds__(256) void quant_rows_kernel(
    const float* __restrict__ in, signed char* __restrict__ q,
    float* __restrict__ rowmax, int K) {
  const int row = blockIdx.x;
  const int t = threadIdx.x;
  const size_t base = (size_t)row * K;
  float4 v = reinterpret_cast<const float4*>(in + base)[t];
  float a = fmaxf(fmaxf(fabsf(v.x), fabsf(v.y)), fmaxf(fabsf(v.z), fabsf(v.w)));
#pragma unroll
  for (int off = 32; off > 0; off >>= 1) a = fmaxf(a, __shfl_xor(a, off, 64));
  __shared__ float smax[4];
  if ((t & 63) == 0) smax[t >> 6] = a;
  __syncthreads();
  float m = fmaxf(fmaxf(smax[0], smax[1]), fmaxf(smax[2], smax[3]));
  float s = 127.0f / m;  // fp32 divide, same as reference
  char4 qq;
  qq.x = (signed char)(int)rintf(v.x * s);
  qq.y = (signed char)(int)rintf(v.y * s);
  qq.z = (signed char)(int)rintf(v.z * s);
  qq.w = (signed char)(int)rintf(v.w * s);
  reinterpret_cast<char4*>(q + base)[t] = qq;
  if (t == 0) rowmax[row] = m;
}

// ---------------- int8 GEMM, 128x128 tile, 4 waves (2x2), BK=64 -------------
__device__ __forceinline__ void gload_lds16(const void* g, void* l) {
  __builtin_amdgcn_global_load_lds(
      (const __attribute__((address_space(1))) unsigned char*)g,
      (__attribute__((address_space(3))) unsigned char*)l, 16, 0, 0);
}

__global__ __launch_bounds__(256) void w8x8_gemm_kernel(
    const signed char* __restrict__ Aq, const signed char* __restrict__ Bq,
    const float* __restrict__ Amax, const float* __restrict__ Bmax,
    const float* __restrict__ bias, float* __restrict__ out,
    int M, int N, int K) {
  __shared__ __align__(16) signed char ldsA[BM * BK];
  __shared__ __align__(16) signed char ldsB[BN * BK];
  const int t = threadIdx.x;
  const int lane = t & 63;
  const int wave = t >> 6;
  const int wrow = wave >> 1, wcol = wave & 1;
  const int bm = blockIdx.y, bn = blockIdx.x;

  const signed char* Abase = Aq + (size_t)bm * BM * K;
  const signed char* Bbase = Bq + (size_t)bn * BN * K;

  i32x4 acc[4][4];
#pragma unroll
  for (int m = 0; m < 4; ++m)
#pragma unroll
    for (int n = 0; n < 4; ++n) acc[m][n] = (i32x4){0, 0, 0, 0};

  // Staging: 128x64 bytes per tile = 512 16B-chunks; 256 threads x 2 chunks.
  // LDS dest is linear (chunk id = t, t+256 -> lane-linear per wave).
  // Source is pre-swizzled: chunk ^= (row>>1)&3 so the swizzled ds_read below
  // sees the right data (bank aliasing 8-way -> 2-way = free).
  const int c0 = t, c1 = t + 256;
  const int r0 = c0 >> 2, r1 = c1 >> 2;
  const int col0 = (((c0 & 3) ^ ((r0 >> 1) & 3)) << 4);
  const int col1 = (((c1 & 3) ^ ((r1 >> 1) & 3)) << 4);

  // Fragment read offsets (swizzled): row = subtile*16 + (lane&15),
  // chunk = (lane>>4) ^ ((row>>1)&3)
  const int fr = lane & 15;
  const int fc = lane >> 4;
  int aoff[4], boff[4];
#pragma unroll
  for (int m = 0; m < 4; ++m) {
    int ra = wrow * 64 + m * 16 + fr;
    aoff[m] = ra * BK + (((fc ^ ((ra >> 1) & 3)) & 3) << 4);
    int rb = wcol * 64 + m * 16 + fr;
    boff[m] = rb * BK + (((fc ^ ((rb >> 1) & 3)) & 3) << 4);
  }

  for (int kt = 0; kt < K; kt += BK) {
    gload_lds16(Abase + (size_t)r0 * K + kt + col0, &ldsA[c0 * 16]);
    gload_lds16(Abase + (size_t)r1 * K + kt + col1, &ldsA[c1 * 16]);
    gload_lds16(Bbase + (size_t)r0 * K + kt + col0, &ldsB[c0 * 16]);
    gload_lds16(Bbase + (size_t)r1 * K + kt + col1, &ldsB[c1 * 16]);
    __syncthreads();  // drains vmcnt (global_load_lds) before ds_read

    i32x4 av[4], bv[4];
#pragma unroll
    for (int m = 0; m < 4; ++m) {
      av[m] = *reinterpret_cast<const i32x4*>(&ldsA[aoff[m]]);
      bv[m] = *reinterpret_cast<const i32x4*>(&ldsB[boff[m]]);
    }
#pragma unroll
    for (int m = 0; m < 4; ++m)
#pragma unroll
      for (int n = 0; n < 4; ++n)
        acc[m][n] =
            __builtin_amdgcn_mfma_i32_16x16x64_i8(av[m], bv[n], acc[m][n], 0, 0, 0);
    __syncthreads();
  }

  // Epilogue: C/D layout col = lane&15, row = (lane>>4)*4 + reg
  const int row_base = bm * BM + wrow * 64;
  const int col_base = bn * BN + wcol * 64;
#pragma unroll
  for (int n = 0; n < 4; ++n) {
    int col = col_base + n * 16 + fr;
    float wm = Bmax[col];
    float bs = bias[col];
#pragma unroll
    for (int m = 0; m < 4; ++m) {
      int rowq = row_base + m * 16 + fc * 4;
#pragma unroll
      for (int r = 0; r < 4; ++r) {
        int row = rowq + r;
        float xm = Amax[row];
        float v = (float)acc[m][n][r] / 16129.0f;  // fp32 div like reference
        float h = __half2float(__float2half_rn(v));  // fp16 rounding step
        out[(size_t)row * N + col] = h * (xm * wm) + bs;
      }
    }
  }
}

extern "C" void kernel_launch(void* const* d_in, const int* in_sizes, int n_in,
                              void* d_out, int out_size, void* d_ws, size_t ws_size,
                              hipStream_t stream) {
  const float* x = (const float*)d_in[0];     // [B,S,K] fp32
  const float* w = (const float*)d_in[1];     // [N,K] fp32
  const float* bias = (const float*)d_in[2];  // [N] fp32
  float* out = (float*)d_out;                 // [B,S,N] fp32

  const int N = in_sizes[2];
  const int K = in_sizes[1] / N;   // 1024
  const int M = in_sizes[0] / K;   // 32768

  // workspace layout: x_q | w_q | x_max | w_max  (~34.7 MB total)
  signed char* xq = (signed char*)d_ws;
  signed char* wq = xq + (size_t)M * K;
  float* xmax = (float*)(wq + (size_t)N * K);
  float* wmax = xmax + M;

  quant_rows_kernel<<<M, 256, 0, stream>>>(x, xq, xmax, K);
  quant_rows_kernel<<<N, 256, 0, stream>>>(w, wq, wmax, K);

  dim3 grid(N / BN, M / BM);
  w8x8_gemm_kernel<<<grid, 256, 0, stream>>>(xq, wq, xmax, wmax, bias, out, M, N, K);
}

// Round 2
// 109.199 us; speedup vs baseline: 1.1205x; 1.1205x over previous
//
#include <hip/hip_runtime.h>
#include <hip/hip_fp16.h>

// W8X8Linear: per-row int8 quant (x and w), int8 GEMM via MFMA, dequant+bias.
// M=B*S=32768, N=1024, K=1024 (derived from in_sizes at launch).
//
// Exact-replication notes:
//  - jnp.round == round-half-even == rintf (v_rndne_f32)
//  - scale computed as 127.0f/max (fp32 div) then fp32 mul, like the reference
//  - int32 accumulation == reference's fp32 einsum (|acc| < 2^24, exact)
//  - dequant: fp32 div by 16129, fp16 RN cast, fp32 * (xmax*wmax) + bias
//
// R1 changes vs R0:
//  - GEMM K-loop: double-buffered 2-phase (stage next tile FIRST, compute
//    current, single vmcnt-drain+barrier at END) -> staging latency hides
//    under ds_read+MFMA instead of being exposed before compute.
//  - XCD-chunked blockIdx swizzle: each XCD gets a contiguous run of bm
//    (A slice 4 MB = one L2) x all bn -> kills the 4x A re-fetch.

typedef int i32x4 __attribute__((ext_vector_type(4)));

#define BM 128
#define BN 128
#define BK 64

// ---------------- quantize: one block per row, K=1024, 256 threads ----------
__global__ __launch_bounds__(256) void quant_rows_kernel(
    const float* __restrict__ in, signed char* __restrict__ q,
    float* __restrict__ rowmax, int K) {
  const int row = blockIdx.x;
  const int t = threadIdx.x;
  const size_t base = (size_t)row * K;
  float4 v = reinterpret_cast<const float4*>(in + base)[t];
  float a = fmaxf(fmaxf(fabsf(v.x), fabsf(v.y)), fmaxf(fabsf(v.z), fabsf(v.w)));
#pragma unroll
  for (int off = 32; off > 0; off >>= 1) a = fmaxf(a, __shfl_xor(a, off, 64));
  __shared__ float smax[4];
  if ((t & 63) == 0) smax[t >> 6] = a;
  __syncthreads();
  float m = fmaxf(fmaxf(smax[0], smax[1]), fmaxf(smax[2], smax[3]));
  float s = 127.0f / m;  // fp32 divide, same as reference
  char4 qq;
  qq.x = (signed char)(int)rintf(v.x * s);
  qq.y = (signed char)(int)rintf(v.y * s);
  qq.z = (signed char)(int)rintf(v.z * s);
  qq.w = (signed char)(int)rintf(v.w * s);
  reinterpret_cast<char4*>(q + base)[t] = qq;
  if (t == 0) rowmax[row] = m;
}

// ---------------- int8 GEMM, 128x128 tile, 4 waves (2x2), BK=64 -------------
__device__ __forceinline__ void gload_lds16(const void* g, void* l) {
  __builtin_amdgcn_global_load_lds(
      (const __attribute__((address_space(1))) unsigned char*)g,
      (__attribute__((address_space(3))) unsigned char*)l, 16, 0, 0);
}

__global__ __launch_bounds__(256) void w8x8_gemm_kernel(
    const signed char* __restrict__ Aq, const signed char* __restrict__ Bq,
    const float* __restrict__ Amax, const float* __restrict__ Bmax,
    const float* __restrict__ bias, float* __restrict__ out,
    int M, int N, int K, int cpx) {
  __shared__ __align__(16) signed char ldsA[2][BM * BK];
  __shared__ __align__(16) signed char ldsB[2][BN * BK];
  const int t = threadIdx.x;
  const int lane = t & 63;
  const int wave = t >> 6;
  const int wrow = wave >> 1, wcol = wave & 1;

  // XCD-chunked swizzle: XCD j (= bid%8) gets contiguous tile chunk.
  const int nbn = N / BN;
  const int bid = blockIdx.x;
  const int tile = (bid & 7) * cpx + (bid >> 3);
  const int bm = tile / nbn, bn = tile % nbn;

  const signed char* Abase = Aq + (size_t)bm * BM * K;
  const signed char* Bbase = Bq + (size_t)bn * BN * K;

  i32x4 acc[4][4];
#pragma unroll
  for (int m = 0; m < 4; ++m)
#pragma unroll
    for (int n = 0; n < 4; ++n) acc[m][n] = (i32x4){0, 0, 0, 0};

  // Staging: 128x64 bytes per tile = 512 16B-chunks; 256 threads x 2 chunks.
  // LDS dest is linear; source is pre-swizzled (chunk ^= (row>>1)&3) so the
  // swizzled ds_read below sees right data (bank aliasing 8-way -> 2-way).
  const int c0 = t, c1 = t + 256;
  const int r0 = c0 >> 2, r1 = c1 >> 2;
  const int col0 = (((c0 & 3) ^ ((r0 >> 1) & 3)) << 4);
  const int col1 = (((c1 & 3) ^ ((r1 >> 1) & 3)) << 4);

  // Fragment read offsets (swizzled): row = subtile*16 + (lane&15),
  // chunk = (lane>>4) ^ ((row>>1)&3)
  const int fr = lane & 15;
  const int fc = lane >> 4;
  int aoff[4], boff[4];
#pragma unroll
  for (int m = 0; m < 4; ++m) {
    int ra = wrow * 64 + m * 16 + fr;
    aoff[m] = ra * BK + (((fc ^ ((ra >> 1) & 3)) & 3) << 4);
    int rb = wcol * 64 + m * 16 + fr;
    boff[m] = rb * BK + (((fc ^ ((rb >> 1) & 3)) & 3) << 4);
  }

  // ---- prologue: stage tile 0 into buf 0, drain, barrier ----
  gload_lds16(Abase + (size_t)r0 * K + 0 + col0, &ldsA[0][c0 * 16]);
  gload_lds16(Abase + (size_t)r1 * K + 0 + col1, &ldsA[0][c1 * 16]);
  gload_lds16(Bbase + (size_t)r0 * K + 0 + col0, &ldsB[0][c0 * 16]);
  gload_lds16(Bbase + (size_t)r1 * K + 0 + col1, &ldsB[0][c1 * 16]);
  __syncthreads();

  const int NT = K / BK;
  int cur = 0;
  for (int tt = 0; tt < NT; ++tt) {
    // 1) issue next tile's staging FIRST (into the other buffer)
    if (tt + 1 < NT) {
      const int kt = (tt + 1) * BK;
      gload_lds16(Abase + (size_t)r0 * K + kt + col0, &ldsA[cur ^ 1][c0 * 16]);
      gload_lds16(Abase + (size_t)r1 * K + kt + col1, &ldsA[cur ^ 1][c1 * 16]);
      gload_lds16(Bbase + (size_t)r0 * K + kt + col0, &ldsB[cur ^ 1][c0 * 16]);
      gload_lds16(Bbase + (size_t)r1 * K + kt + col1, &ldsB[cur ^ 1][c1 * 16]);
    }
    // 2) compute current tile (ds_read + MFMA); staging latency hides here
    i32x4 av[4], bv[4];
#pragma unroll
    for (int m = 0; m < 4; ++m) {
      av[m] = *reinterpret_cast<const i32x4*>(&ldsA[cur][aoff[m]]);
      bv[m] = *reinterpret_cast<const i32x4*>(&ldsB[cur][boff[m]]);
    }
#pragma unroll
    for (int m = 0; m < 4; ++m)
#pragma unroll
      for (int n = 0; n < 4; ++n)
        acc[m][n] = __builtin_amdgcn_mfma_i32_16x16x64_i8(av[m], bv[n],
                                                          acc[m][n], 0, 0, 0);
    // 3) single drain+barrier at END of iteration (next tile now ready;
    //    also makes it safe for next iter to overwrite buf we just read)
    __syncthreads();
    cur ^= 1;
  }

  // Epilogue: C/D layout col = lane&15, row = (lane>>4)*4 + reg
  const int row_base = bm * BM + wrow * 64;
  const int col_base = bn * BN + wcol * 64;
#pragma unroll
  for (int n = 0; n < 4; ++n) {
    int col = col_base + n * 16 + fr;
    float wm = Bmax[col];
    float bs = bias[col];
#pragma unroll
    for (int m = 0; m < 4; ++m) {
      int rowq = row_base + m * 16 + fc * 4;
#pragma unroll
      for (int r = 0; r < 4; ++r) {
        int row = rowq + r;
        float xm = Amax[row];
        float v = (float)acc[m][n][r] / 16129.0f;     // fp32 div like reference
        float h = __half2float(__float2half_rn(v));   // fp16 rounding step
        out[(size_t)row * N + col] = h * (xm * wm) + bs;
      }
    }
  }
}

extern "C" void kernel_launch(void* const* d_in, const int* in_sizes, int n_in,
                              void* d_out, int out_size, void* d_ws, size_t ws_size,
                              hipStream_t stream) {
  const float* x = (const float*)d_in[0];     // [B,S,K] fp32
  const float* w = (const float*)d_in[1];     // [N,K] fp32
  const float* bias = (const float*)d_in[2];  // [N] fp32
  float* out = (float*)d_out;                 // [B,S,N] fp32

  const int N = in_sizes[2];
  const int K = in_sizes[1] / N;   // 1024
  const int M = in_sizes[0] / K;   // 32768

  // workspace layout: x_q | w_q | x_max | w_max  (~34.7 MB total)
  signed char* xq = (signed char*)d_ws;
  signed char* wq = xq + (size_t)M * K;
  float* xmax = (float*)(wq + (size_t)N * K);
  float* wmax = xmax + M;

  quant_rows_kernel<<<M, 256, 0, stream>>>(x, xq, xmax, K);
  quant_rows_kernel<<<N, 256, 0, stream>>>(w, wq, wmax, K);

  const int nwg = (M / BM) * (N / BN);  // 2048, divisible by 8
  const int cpx = nwg / 8;
  w8x8_gemm_kernel<<<nwg, 256, 0, stream>>>(xq, wq, xmax, wmax, bias, out,
                                            M, N, K, cpx);
}